// Round 5
// baseline (509.709 us; speedup 1.0000x reference)
//
#include <hip/hip_runtime.h>
#include <hip/hip_bf16.h>
#include <math.h>

#define Bc 32
#define Cc 64
#define Sc 128
#define Zc 64
#define Dc 256
#define VOc 5000

typedef __attribute__((ext_vector_type(8))) short v8s;   // 8 bf16 = 4 VGPR MFMA frag
typedef __attribute__((ext_vector_type(4))) float f4;    // 16x16 accum

union FQ { uint4 q; v8s s; };
struct HL { v8s hi, lo; };

__device__ __forceinline__ unsigned short bf_bits(__hip_bfloat16 h) {
  union { __hip_bfloat16 b; unsigned short u; } cv; cv.b = h; return cv.u;
}

__device__ __forceinline__ void split_hl(float x, unsigned short& h, unsigned short& l) {
  __hip_bfloat16 hh = __float2bfloat16(x);
  float hf = __bfloat162float(hh);
  __hip_bfloat16 ll = __float2bfloat16(x - hf);
  h = bf_bits(hh); l = bf_bits(ll);
}

// pack fp32 -> (hi bf16 | lo bf16 << 16)
__device__ __forceinline__ unsigned pack_hl(float x) {
  unsigned short h, l; split_hl(x, h, l);
  return (unsigned)h | ((unsigned)l << 16);
}

// 8 packed u32 -> hi-frag + lo-frag
__device__ __forceinline__ HL unpack8(uint4 q0, uint4 q1) {
  FQ h, l;
  h.q.x = __builtin_amdgcn_perm(q0.y, q0.x, 0x05040100u);
  h.q.y = __builtin_amdgcn_perm(q0.w, q0.z, 0x05040100u);
  h.q.z = __builtin_amdgcn_perm(q1.y, q1.x, 0x05040100u);
  h.q.w = __builtin_amdgcn_perm(q1.w, q1.z, 0x05040100u);
  l.q.x = __builtin_amdgcn_perm(q0.y, q0.x, 0x07060302u);
  l.q.y = __builtin_amdgcn_perm(q0.w, q0.z, 0x07060302u);
  l.q.z = __builtin_amdgcn_perm(q1.y, q1.x, 0x07060302u);
  l.q.w = __builtin_amdgcn_perm(q1.w, q1.z, 0x07060302u);
  HL r; r.hi = h.s; r.lo = l.s; return r;
}

// 3-term split product, plane operands
__device__ __forceinline__ f4 mm3p(v8s ah, v8s al, v8s bh, v8s bl, f4 c) {
  c = __builtin_amdgcn_mfma_f32_16x16x32_bf16(ah, bh, c, 0, 0, 0);
  c = __builtin_amdgcn_mfma_f32_16x16x32_bf16(ah, bl, c, 0, 0, 0);
  c = __builtin_amdgcn_mfma_f32_16x16x32_bf16(al, bh, c, 0, 0, 0);
  return c;
}
__device__ __forceinline__ f4 mm3h(const HL& A, v8s bh, v8s bl, f4 c) {
  return mm3p(A.hi, A.lo, bh, bl, c);
}
__device__ __forceinline__ f4 mm3hh(const HL& A, const HL& B, f4 c) {
  return mm3p(A.hi, A.lo, B.hi, B.lo, c);
}

// ---------------------------------------------------------------------------
// Merged transform (fp32 VALU GEMM core as R4; new epilogues):
//  seg0: relu(row@FW+Fb) -> bf16 hi/lo PLANES  (Am_hi/lo | FB_hi/lo)
//  seg1: row@GW[0:256] + Gb -> fp32            (Ta' | Tb')   [Gb folded]
//  seg2: row@GW[256:512]  -> taskA: UaT hi/lo planes [b][g][s]
//                            taskB: Ub packed hi|lo u32 [row][g]
// ---------------------------------------------------------------------------
__global__ __launch_bounds__(256) void transform_kernel(
    const float* __restrict__ EmbA, const int* __restrict__ inp,
    const float* __restrict__ EmbB,
    const float* __restrict__ FW, const float* __restrict__ Fb,
    const float* __restrict__ GW, const float* __restrict__ Gb,
    unsigned short* __restrict__ Am_hi, unsigned short* __restrict__ Am_lo,
    float* __restrict__ Ta,
    unsigned short* __restrict__ UaT_hi, unsigned short* __restrict__ UaT_lo,
    unsigned short* __restrict__ FB_hi, unsigned short* __restrict__ FB_lo,
    float* __restrict__ Tb, unsigned* __restrict__ Ub_hl)
{
  const bool taskA = (blockIdx.x < 64);
  const int rb = taskA ? blockIdx.x : (blockIdx.x - 64);
  const int nrows = taskA ? 4096 : 5000;
  const float* __restrict__ Emb = taskA ? EmbA : EmbB;
  const int* __restrict__ idx = taskA ? inp : nullptr;

  const int cb = blockIdx.y;
  const int row0 = rb * 64;
  const int seg = cb >> 1;               // 0:FW 1:GW1 2:GW2
  const int colbase = (cb & 1) * 128;
  const float* W = (seg == 0) ? FW : GW;
  const int rowoff = (seg == 2) ? Dc : 0;

  __shared__ float As[32][68];
  __shared__ float Ws[32][132];

  const int t = threadIdx.x;
  const int mt = t >> 4, nt = t & 15;
  const int m0 = mt * 4, n0 = nt * 8;
  float acc[4][8];
#pragma unroll
  for (int i = 0; i < 4; ++i)
#pragma unroll
    for (int j = 0; j < 8; ++j) acc[i][j] = 0.f;

  for (int k0 = 0; k0 < Dc; k0 += 32) {
#pragma unroll
    for (int i = 0; i < 2; ++i) {
      int f = t + i * 256;
      int m = f >> 3, kq = f & 7;
      int r = row0 + m; if (r > nrows - 1) r = nrows - 1;
      int src = idx ? idx[r] : r;
      float4 v = *(const float4*)&Emb[(size_t)src * Dc + k0 + kq * 4];
      As[kq * 4 + 0][m] = v.x; As[kq * 4 + 1][m] = v.y;
      As[kq * 4 + 2][m] = v.z; As[kq * 4 + 3][m] = v.w;
    }
#pragma unroll
    for (int i = 0; i < 4; ++i) {
      int f = t + i * 256;
      int k = f >> 5, nq = f & 31;
      float4 v = *(const float4*)&W[(size_t)(rowoff + k0 + k) * Dc + colbase + nq * 4];
      *(float4*)&Ws[k][nq * 4] = v;
    }
    __syncthreads();
#pragma unroll
    for (int k = 0; k < 32; ++k) {
      float a[4], w[8];
      *(float4*)&a[0] = *(const float4*)&As[k][m0];
      *(float4*)&w[0] = *(const float4*)&Ws[k][n0];
      *(float4*)&w[4] = *(const float4*)&Ws[k][n0 + 4];
#pragma unroll
      for (int i = 0; i < 4; ++i)
#pragma unroll
        for (int j = 0; j < 8; ++j) acc[i][j] = fmaf(a[i], w[j], acc[i][j]);
    }
    __syncthreads();
  }

  if (seg == 1) {
    float* outp = taskA ? Ta : Tb;
    float gb[8];
#pragma unroll
    for (int j = 0; j < 8; ++j) gb[j] = Gb[colbase + n0 + j];
#pragma unroll
    for (int i = 0; i < 4; ++i) {
      int r = row0 + m0 + i;
      if (r >= nrows) continue;
      float o[8];
#pragma unroll
      for (int j = 0; j < 8; ++j) o[j] = acc[i][j] + gb[j];
      *(float4*)&outp[(size_t)r * Dc + colbase + n0]     = *(float4*)&o[0];
      *(float4*)&outp[(size_t)r * Dc + colbase + n0 + 4] = *(float4*)&o[4];
    }
  } else if (seg == 0) {
    float bias[8];
#pragma unroll
    for (int j = 0; j < 8; ++j) bias[j] = Fb[colbase + n0 + j];
    unsigned short* Hi = taskA ? Am_hi : FB_hi;
    unsigned short* Lo = taskA ? Am_lo : FB_lo;
#pragma unroll
    for (int i = 0; i < 4; ++i) {
      int r = row0 + m0 + i;
      if (r >= nrows) continue;
      unsigned short hs[8], ls[8];
#pragma unroll
      for (int j = 0; j < 8; ++j)
        split_hl(fmaxf(acc[i][j] + bias[j], 0.f), hs[j], ls[j]);
      *(uint4*)&Hi[(size_t)r * Dc + colbase + n0] = *(uint4*)hs;
      *(uint4*)&Lo[(size_t)r * Dc + colbase + n0] = *(uint4*)ls;
    }
  } else if (!taskA) {
#pragma unroll
    for (int i = 0; i < 4; ++i) {
      int r = row0 + m0 + i;
      if (r >= nrows) continue;
      unsigned pk[8];
#pragma unroll
      for (int j = 0; j < 8; ++j) pk[j] = pack_hl(acc[i][j]);
      *(uint4*)&Ub_hl[(size_t)r * Dc + colbase + n0]     = *(uint4*)&pk[0];
      *(uint4*)&Ub_hl[(size_t)r * Dc + colbase + n0 + 4] = *(uint4*)&pk[4];
    }
  } else {
    // UaT planes: [b][g][s]
#pragma unroll
    for (int i = 0; i < 4; ++i) {
      int r = row0 + m0 + i;
      int bI = r >> 7, sI = r & 127;
#pragma unroll
      for (int j = 0; j < 8; ++j) {
        unsigned short h, l;
        split_hl(acc[i][j], h, l);
        size_t o = ((size_t)(bI * 256 + colbase + n0 + j)) * 128 + sI;
        UaT_hi[o] = h; UaT_lo[o] = l;
      }
    }
  }
}

// ---------------------------------------------------------------------------
// Fused per-(b,c) MFMA kernel, 512 threads (8 waves), 2 blocks/CU.
// LDS (74784 B): E[128][66] u32 packed (persists), EU = Et[64][130] -> UbT
// half [128][66] (time-shared), + stats/reduction scratch. All strides give
// 2-way (free) bank aliasing.
// ---------------------------------------------------------------------------
#define SMEM_WORDS (8448 + 8448 + 1024 + 256 + 256 + 128 + 64 + 64 + 8)
#define SMEM_BYTES (SMEM_WORDS * 4)

__global__ __launch_bounds__(512, 4) void fused_kernel(
    const int* __restrict__ cand,
    const unsigned short* __restrict__ Am_hi, const unsigned short* __restrict__ Am_lo,
    const unsigned short* __restrict__ FB_hi, const unsigned short* __restrict__ FB_lo,
    const unsigned short* __restrict__ UaT_hi, const unsigned short* __restrict__ UaT_lo,
    const unsigned* __restrict__ Ub_hl,
    const float* __restrict__ Ta, const float* __restrict__ Tb,
    float* __restrict__ V1, float* __restrict__ V2)
{
  extern __shared__ char smem[];
  unsigned* E   = (unsigned*)smem;           // 128*66
  unsigned* EU  = E + 8448;                  // Et[64][130] then UbT[128][66]
  float* vred = (float*)(EU + 8448);         // 1024
  float* rsp  = vred + 1024;                 // 2*128
  float* csp  = rsp + 256;                   // 4*64
  float* rrcp = csp + 256;                   // 128
  float* crcp = rrcp + 128;                  // 64
  int*   cidx = (int*)(crcp + 64);           // 64
  float* gmax = (float*)(cidx + 64);         // 8

  const int bc = ((blockIdx.x & 7) << 8) | (blockIdx.x >> 3);  // XCD swizzle
  const int b = bc >> 6, t = threadIdx.x;
  const int w = t >> 6, l = t & 63, a = l & 15, hq = l >> 4;

  if (t < 64) cidx[t] = cand[(size_t)bc * 64 + t];
  __syncthreads();

  // ---- phase 1: e = Am[b] @ FB^T. wave: 2 s-tiles (sw2) x 2 z-tiles (zh) ----
  const int sw2 = w >> 1, zh = w & 1;
  f4 acc[2][2];
#pragma unroll
  for (int i = 0; i < 2; ++i)
#pragma unroll
    for (int j = 0; j < 2; ++j)
#pragma unroll
      for (int r = 0; r < 4; ++r) acc[i][j][r] = 0.f;
  {
    const size_t r0 = ((size_t)(b * 128 + (2 * sw2) * 16 + a)) * 256;
    const size_t r1 = r0 + 16 * 256;
    size_t zr0 = (size_t)cidx[(2 * zh) * 16 + a] * 256;
    size_t zr1 = (size_t)cidx[(2 * zh + 1) * 16 + a] * 256;
#pragma unroll
    for (int ch = 0; ch < 8; ++ch) {
      int k0 = ch * 32 + hq * 8;
      v8s a0h = *(const v8s*)&Am_hi[r0 + k0], a0l = *(const v8s*)&Am_lo[r0 + k0];
      v8s a1h = *(const v8s*)&Am_hi[r1 + k0], a1l = *(const v8s*)&Am_lo[r1 + k0];
      v8s b0h = *(const v8s*)&FB_hi[zr0 + k0], b0l = *(const v8s*)&FB_lo[zr0 + k0];
      v8s b1h = *(const v8s*)&FB_hi[zr1 + k0], b1l = *(const v8s*)&FB_lo[zr1 + k0];
      acc[0][0] = mm3p(a0h, a0l, b0h, b0l, acc[0][0]);
      acc[0][1] = mm3p(a0h, a0l, b1h, b1l, acc[0][1]);
      acc[1][0] = mm3p(a1h, a1l, b0h, b0l, acc[1][0]);
      acc[1][1] = mm3p(a1h, a1l, b1h, b1l, acc[1][1]);
    }
  }

  // ---- softmax: global max; E = exp(e-M); row/col sums -> reciprocals ----
  {
    float m = -1e30f;
#pragma unroll
    for (int i = 0; i < 2; ++i)
#pragma unroll
      for (int j = 0; j < 2; ++j)
#pragma unroll
        for (int r = 0; r < 4; ++r) m = fmaxf(m, acc[i][j][r]);
#pragma unroll
    for (int d = 1; d < 64; d <<= 1) m = fmaxf(m, __shfl_xor(m, d));
    if (l == 0) gmax[w] = m;
    __syncthreads();
    float M = gmax[0];
#pragma unroll
    for (int q = 1; q < 8; ++q) M = fmaxf(M, gmax[q]);

#pragma unroll
    for (int i = 0; i < 2; ++i)
#pragma unroll
      for (int j = 0; j < 2; ++j)
#pragma unroll
        for (int r = 0; r < 4; ++r) acc[i][j][r] = __expf(acc[i][j][r] - M);

    // rowsum partial (over this wave's 32 z)
#pragma unroll
    for (int si = 0; si < 2; ++si)
#pragma unroll
      for (int r = 0; r < 4; ++r) {
        float rs = acc[si][0][r] + acc[si][1][r];
        rs += __shfl_xor(rs, 1); rs += __shfl_xor(rs, 2);
        rs += __shfl_xor(rs, 4); rs += __shfl_xor(rs, 8);
        if (a == 0) rsp[zh * 128 + (2 * sw2 + si) * 16 + hq * 4 + r] = rs;
      }
    // colsum partial (over this wave's 32 s)
#pragma unroll
    for (int zi = 0; zi < 2; ++zi) {
      float c = acc[0][zi][0] + acc[0][zi][1] + acc[0][zi][2] + acc[0][zi][3]
              + acc[1][zi][0] + acc[1][zi][1] + acc[1][zi][2] + acc[1][zi][3];
      c += __shfl_xor(c, 16); c += __shfl_xor(c, 32);
      if (l < 16) csp[sw2 * 64 + (2 * zh + zi) * 16 + a] = c;
    }
    // packed E + Et
#pragma unroll
    for (int si = 0; si < 2; ++si)
#pragma unroll
      for (int zi = 0; zi < 2; ++zi)
#pragma unroll
        for (int r = 0; r < 4; ++r) {
          int s = (2 * sw2 + si) * 16 + hq * 4 + r;
          int z = (2 * zh + zi) * 16 + a;
          unsigned pk = pack_hl(acc[si][zi][r]);
          E[s * 66 + z] = pk;
          EU[z * 130 + s] = pk;
        }
    __syncthreads();
    if (t < 128) rrcp[t] = 1.f / (rsp[t] + rsp[128 + t]);
    if (t >= 256 && t < 320) {
      int z = t - 256;
      crcp[z] = 1.f / (csp[z] + csp[64 + z] + csp[128 + z] + csp[192 + z]);
    }
    __syncthreads();
  }

  // ---- phase 3a: P2 = Et @ Ua (B from global UaT planes) ----
  {
    const int zt = w & 3, gh3 = w >> 2;
    HL af[4];
#pragma unroll
    for (int ch = 0; ch < 4; ++ch) {
      const unsigned* p = EU + (zt * 16 + a) * 130 + ch * 32 + hq * 8;
      af[ch] = unpack8(*(const uint4*)p, *(const uint4*)(p + 4));
    }
    float crz[4]; const float* tbp[4];
#pragma unroll
    for (int r = 0; r < 4; ++r) {
      int z = zt * 16 + hq * 4 + r;
      crz[r] = crcp[z];
      tbp[r] = Tb + (size_t)cidx[z] * 256;
    }
#pragma unroll
    for (int gt2 = 0; gt2 < 8; ++gt2) {
      int gcol = (gh3 * 8 + gt2) * 16 + a;
      const unsigned short* uh = UaT_hi + ((size_t)(b * 256 + gcol)) * 128;
      const unsigned short* ul = UaT_lo + ((size_t)(b * 256 + gcol)) * 128;
      f4 c = {0.f, 0.f, 0.f, 0.f};
#pragma unroll
      for (int ch = 0; ch < 4; ++ch) {
        int k0 = ch * 32 + hq * 8;
        c = mm3h(af[ch], *(const v8s*)&uh[k0], *(const v8s*)&ul[k0], c);
      }
      float sv = 0.f;
#pragma unroll
      for (int r = 0; r < 4; ++r)
        sv += fmaxf(fmaf(c[r], crz[r], tbp[r][gcol]), 0.f);
      sv += __shfl_xor(sv, 16); sv += __shfl_xor(sv, 32);
      if (l < 16) vred[zt * 256 + gcol] = sv;
    }
    __syncthreads();
    if (t < 256)
      V2[(size_t)bc * 256 + t] = vred[t] + vred[256 + t] + vred[512 + t] + vred[768 + t];
  }

  // ---- phase 3b: P1 = E @ UbT (UbT staged per g-half into EU) ----
  for (int h = 0; h < 2; ++h) {
#pragma unroll
    for (int it = 0; it < 16; ++it) {
      int flat = it * 512 + t;
      int z = flat >> 7, gl = flat & 127;
      EU[gl * 66 + z] = Ub_hl[(size_t)cidx[z] * 256 + h * 128 + gl];
    }
    __syncthreads();

    const int sT = w;
    HL af1[2];
#pragma unroll
    for (int ch = 0; ch < 2; ++ch) {
      const unsigned* p = E + (sT * 16 + a) * 66 + ch * 32 + hq * 8;
      af1[ch] = unpack8(*(const uint4*)p, *(const uint4*)(p + 4));
    }
    float rr[4]; const float* tap[4];
#pragma unroll
    for (int r = 0; r < 4; ++r) {
      int s = sT * 16 + hq * 4 + r;
      rr[r] = rrcp[s];
      tap[r] = Ta + ((size_t)(b * 128 + s)) * 256 + h * 128;
    }
#pragma unroll
    for (int gt2 = 0; gt2 < 8; ++gt2) {
      int gl = gt2 * 16 + a;
      f4 c = {0.f, 0.f, 0.f, 0.f};
#pragma unroll
      for (int ch = 0; ch < 2; ++ch) {
        const unsigned* p = EU + gl * 66 + ch * 32 + hq * 8;
        HL B = unpack8(*(const uint4*)p, *(const uint4*)(p + 4));
        c = mm3hh(af1[ch], B, c);
      }
      float sv = 0.f;
#pragma unroll
      for (int r = 0; r < 4; ++r)
        sv += fmaxf(fmaf(c[r], rr[r], tap[r][gl]), 0.f);
      sv += __shfl_xor(sv, 16); sv += __shfl_xor(sv, 32);
      if (l < 16) vred[sT * 128 + gl] = sv;
    }
    __syncthreads();
    if (t < 128) {
      float s = 0.f;
#pragma unroll
      for (int q = 0; q < 8; ++q) s += vred[q * 128 + t];
      V1[(size_t)bc * 256 + h * 128 + t] = s;
    }
    // EU reads all done at the post-compute barrier; next stage may proceed.
  }
}

// ---------------------------------------------------------------------------
// y[bc] = V1[bc]·HW[0:256] + V2[bc]·HW[256:512] + Hb
// ---------------------------------------------------------------------------
__global__ __launch_bounds__(256) void final_kernel(
    const float* __restrict__ V1, const float* __restrict__ V2,
    const float* __restrict__ HW, const float* __restrict__ Hb,
    float* __restrict__ y)
{
  const int t = threadIdx.x;
  const int w = t >> 6, l = t & 63;
  const int bc = blockIdx.x * 4 + w;
  float4 v1 = *(const float4*)&V1[(size_t)bc * Dc + l * 4];
  float4 h1 = *(const float4*)&HW[l * 4];
  float4 v2 = *(const float4*)&V2[(size_t)bc * Dc + l * 4];
  float4 h2 = *(const float4*)&HW[Dc + l * 4];
  float sum = v1.x * h1.x + v1.y * h1.y + v1.z * h1.z + v1.w * h1.w
            + v2.x * h2.x + v2.y * h2.y + v2.z * h2.z + v2.w * h2.w;
#pragma unroll
  for (int off = 32; off > 0; off >>= 1) sum += __shfl_down(sum, off);
  if (l == 0) y[bc] = sum + Hb[0];
}

extern "C" void kernel_launch(void* const* d_in, const int* in_sizes, int n_in,
                              void* d_out, int out_size, void* d_ws, size_t ws_size,
                              hipStream_t stream) {
  (void)in_sizes; (void)n_in; (void)out_size; (void)ws_size;
  const int*   inp  = (const int*)d_in[0];
  const int*   cand = (const int*)d_in[1];
  const float* EmbA = (const float*)d_in[4];
  const float* EmbB = (const float*)d_in[5];
  const float* FW   = (const float*)d_in[6];
  const float* Fb   = (const float*)d_in[7];
  const float* GW   = (const float*)d_in[8];
  const float* Gb   = (const float*)d_in[9];
  const float* HW   = (const float*)d_in[10];
  const float* Hb   = (const float*)d_in[11];
  float* y = (float*)d_out;

  const size_t nA = (size_t)Bc * Sc * Dc;   // 1,048,576 elems
  const size_t nB = (size_t)VOc * Dc;       // 1,280,000 elems
  const size_t nV = (size_t)Bc * Cc * Dc;   //   524,288 elems
  char* ws = (char*)d_ws;
  unsigned short* Am_hi = (unsigned short*)ws;              ws += nA * 2;
  unsigned short* Am_lo = (unsigned short*)ws;              ws += nA * 2;
  unsigned short* FB_hi = (unsigned short*)ws;              ws += nB * 2;
  unsigned short* FB_lo = (unsigned short*)ws;              ws += nB * 2;
  unsigned short* UaT_hi = (unsigned short*)ws;             ws += nA * 2;
  unsigned short* UaT_lo = (unsigned short*)ws;             ws += nA * 2;
  unsigned*       Ub_hl  = (unsigned*)ws;                   ws += nB * 4;
  float*          Ta     = (float*)ws;                      ws += nA * 4;
  float*          Tb     = (float*)ws;                      ws += nB * 4;
  float*          V1     = (float*)ws;                      ws += nV * 4;
  float*          V2     = (float*)ws;                      // total ~31.8 MB

  hipFuncSetAttribute((const void*)fused_kernel,
                      hipFuncAttributeMaxDynamicSharedMemorySize, SMEM_BYTES);

  transform_kernel<<<dim3(143, 6), 256, 0, stream>>>(
      EmbA, inp, EmbB, FW, Fb, GW, Gb,
      Am_hi, Am_lo, Ta, UaT_hi, UaT_lo, FB_hi, FB_lo, Tb, Ub_hl);
  fused_kernel<<<Bc * Cc, 512, SMEM_BYTES, stream>>>(
      cand, Am_hi, Am_lo, FB_hi, FB_lo, UaT_hi, UaT_lo, Ub_hl, Ta, Tb, V1, V2);
  final_kernel<<<(Bc * Cc) / 4, 256, 0, stream>>>(V1, V2, HW, Hb, y);
}

// Round 6
// 373.839 us; speedup vs baseline: 1.3634x; 1.3634x over previous
//
#include <hip/hip_runtime.h>
#include <hip/hip_bf16.h>
#include <math.h>

#define Bc 32
#define Cc 64
#define Sc 128
#define Zc 64
#define Dc 256
#define VOc 5000

typedef __attribute__((ext_vector_type(8))) short v8s;   // 8 bf16 = 4 VGPR MFMA frag
typedef __attribute__((ext_vector_type(4))) float f4;    // 16x16 accum

union FQ { uint4 q; v8s s; };
struct HL { v8s hi, lo; };

__device__ __forceinline__ unsigned short bf_bits(__hip_bfloat16 h) {
  union { __hip_bfloat16 b; unsigned short u; } cv; cv.b = h; return cv.u;
}

__device__ __forceinline__ void split_hl(float x, unsigned short& h, unsigned short& l) {
  __hip_bfloat16 hh = __float2bfloat16(x);
  float hf = __bfloat162float(hh);
  __hip_bfloat16 ll = __float2bfloat16(x - hf);
  h = bf_bits(hh); l = bf_bits(ll);
}

__device__ __forceinline__ unsigned pack_hl(float x) {
  unsigned short h, l; split_hl(x, h, l);
  return (unsigned)h | ((unsigned)l << 16);
}

// 8 packed u32 -> hi-frag + lo-frag
__device__ __forceinline__ HL unpack8(uint4 q0, uint4 q1) {
  FQ h, l;
  h.q.x = __builtin_amdgcn_perm(q0.y, q0.x, 0x05040100u);
  h.q.y = __builtin_amdgcn_perm(q0.w, q0.z, 0x05040100u);
  h.q.z = __builtin_amdgcn_perm(q1.y, q1.x, 0x05040100u);
  h.q.w = __builtin_amdgcn_perm(q1.w, q1.z, 0x05040100u);
  l.q.x = __builtin_amdgcn_perm(q0.y, q0.x, 0x07060302u);
  l.q.y = __builtin_amdgcn_perm(q0.w, q0.z, 0x07060302u);
  l.q.z = __builtin_amdgcn_perm(q1.y, q1.x, 0x07060302u);
  l.q.w = __builtin_amdgcn_perm(q1.w, q1.z, 0x07060302u);
  HL r; r.hi = h.s; r.lo = l.s; return r;
}

// 3-term split product (fp32 accum): AhBh + AhBl + AlBh
__device__ __forceinline__ f4 mm3p(v8s ah, v8s al, v8s bh, v8s bl, f4 c) {
  c = __builtin_amdgcn_mfma_f32_16x16x32_bf16(ah, bh, c, 0, 0, 0);
  c = __builtin_amdgcn_mfma_f32_16x16x32_bf16(ah, bl, c, 0, 0, 0);
  c = __builtin_amdgcn_mfma_f32_16x16x32_bf16(al, bh, c, 0, 0, 0);
  return c;
}
__device__ __forceinline__ f4 mm3h(const HL& A, v8s bh, v8s bl, f4 c) {
  return mm3p(A.hi, A.lo, bh, bl, c);
}

// ---------------------------------------------------------------------------
// Merged transform (unchanged from R5):
//  seg0: relu(row@FW+Fb) -> bf16 hi/lo planes  (Am_hi/lo | FB_hi/lo)
//  seg1: row@GW[0:256] + Gb -> fp32            (Ta' | Tb')
//  seg2: row@GW[256:512] -> taskA: UaT hi/lo planes [b][g][s]
//                           taskB: Ub packed hi|lo u32 [row][g]
// ---------------------------------------------------------------------------
__global__ __launch_bounds__(256) void transform_kernel(
    const float* __restrict__ EmbA, const int* __restrict__ inp,
    const float* __restrict__ EmbB,
    const float* __restrict__ FW, const float* __restrict__ Fb,
    const float* __restrict__ GW, const float* __restrict__ Gb,
    unsigned short* __restrict__ Am_hi, unsigned short* __restrict__ Am_lo,
    float* __restrict__ Ta,
    unsigned short* __restrict__ UaT_hi, unsigned short* __restrict__ UaT_lo,
    unsigned short* __restrict__ FB_hi, unsigned short* __restrict__ FB_lo,
    float* __restrict__ Tb, unsigned* __restrict__ Ub_hl)
{
  const bool taskA = (blockIdx.x < 64);
  const int rb = taskA ? blockIdx.x : (blockIdx.x - 64);
  const int nrows = taskA ? 4096 : 5000;
  const float* __restrict__ Emb = taskA ? EmbA : EmbB;
  const int* __restrict__ idx = taskA ? inp : nullptr;

  const int cb = blockIdx.y;
  const int row0 = rb * 64;
  const int seg = cb >> 1;
  const int colbase = (cb & 1) * 128;
  const float* W = (seg == 0) ? FW : GW;
  const int rowoff = (seg == 2) ? Dc : 0;

  __shared__ float As[32][68];
  __shared__ float Ws[32][132];

  const int t = threadIdx.x;
  const int mt = t >> 4, nt = t & 15;
  const int m0 = mt * 4, n0 = nt * 8;
  float acc[4][8];
#pragma unroll
  for (int i = 0; i < 4; ++i)
#pragma unroll
    for (int j = 0; j < 8; ++j) acc[i][j] = 0.f;

  for (int k0 = 0; k0 < Dc; k0 += 32) {
#pragma unroll
    for (int i = 0; i < 2; ++i) {
      int f = t + i * 256;
      int m = f >> 3, kq = f & 7;
      int r = row0 + m; if (r > nrows - 1) r = nrows - 1;
      int src = idx ? idx[r] : r;
      float4 v = *(const float4*)&Emb[(size_t)src * Dc + k0 + kq * 4];
      As[kq * 4 + 0][m] = v.x; As[kq * 4 + 1][m] = v.y;
      As[kq * 4 + 2][m] = v.z; As[kq * 4 + 3][m] = v.w;
    }
#pragma unroll
    for (int i = 0; i < 4; ++i) {
      int f = t + i * 256;
      int k = f >> 5, nq = f & 31;
      float4 v = *(const float4*)&W[(size_t)(rowoff + k0 + k) * Dc + colbase + nq * 4];
      *(float4*)&Ws[k][nq * 4] = v;
    }
    __syncthreads();
#pragma unroll
    for (int k = 0; k < 32; ++k) {
      float a[4], w[8];
      *(float4*)&a[0] = *(const float4*)&As[k][m0];
      *(float4*)&w[0] = *(const float4*)&Ws[k][n0];
      *(float4*)&w[4] = *(const float4*)&Ws[k][n0 + 4];
#pragma unroll
      for (int i = 0; i < 4; ++i)
#pragma unroll
        for (int j = 0; j < 8; ++j) acc[i][j] = fmaf(a[i], w[j], acc[i][j]);
    }
    __syncthreads();
  }

  if (seg == 1) {
    float* outp = taskA ? Ta : Tb;
    float gb[8];
#pragma unroll
    for (int j = 0; j < 8; ++j) gb[j] = Gb[colbase + n0 + j];
#pragma unroll
    for (int i = 0; i < 4; ++i) {
      int r = row0 + m0 + i;
      if (r >= nrows) continue;
      float o[8];
#pragma unroll
      for (int j = 0; j < 8; ++j) o[j] = acc[i][j] + gb[j];
      *(float4*)&outp[(size_t)r * Dc + colbase + n0]     = *(float4*)&o[0];
      *(float4*)&outp[(size_t)r * Dc + colbase + n0 + 4] = *(float4*)&o[4];
    }
  } else if (seg == 0) {
    float bias[8];
#pragma unroll
    for (int j = 0; j < 8; ++j) bias[j] = Fb[colbase + n0 + j];
    unsigned short* Hi = taskA ? Am_hi : FB_hi;
    unsigned short* Lo = taskA ? Am_lo : FB_lo;
#pragma unroll
    for (int i = 0; i < 4; ++i) {
      int r = row0 + m0 + i;
      if (r >= nrows) continue;
      unsigned short hs[8], ls[8];
#pragma unroll
      for (int j = 0; j < 8; ++j)
        split_hl(fmaxf(acc[i][j] + bias[j], 0.f), hs[j], ls[j]);
      *(uint4*)&Hi[(size_t)r * Dc + colbase + n0] = *(uint4*)hs;
      *(uint4*)&Lo[(size_t)r * Dc + colbase + n0] = *(uint4*)ls;
    }
  } else if (!taskA) {
#pragma unroll
    for (int i = 0; i < 4; ++i) {
      int r = row0 + m0 + i;
      if (r >= nrows) continue;
      unsigned pk[8];
#pragma unroll
      for (int j = 0; j < 8; ++j) pk[j] = pack_hl(acc[i][j]);
      *(uint4*)&Ub_hl[(size_t)r * Dc + colbase + n0]     = *(uint4*)&pk[0];
      *(uint4*)&Ub_hl[(size_t)r * Dc + colbase + n0 + 4] = *(uint4*)&pk[4];
    }
  } else {
#pragma unroll
    for (int i = 0; i < 4; ++i) {
      int r = row0 + m0 + i;
      int bI = r >> 7, sI = r & 127;
#pragma unroll
      for (int j = 0; j < 8; ++j) {
        unsigned short h, l;
        split_hl(acc[i][j], h, l);
        size_t o = ((size_t)(bI * 256 + colbase + n0 + j)) * 128 + sI;
        UaT_hi[o] = h; UaT_lo[o] = l;
      }
    }
  }
}

// ---------------------------------------------------------------------------
// Fused per-(b,c) MFMA kernel, 512 threads (8 waves), 2 blocks/CU (78.9 KB).
// LDS: E_pk[128][68] u32 (persist); SH 9216 w time-shared:
//   phase1: FBh planes [32][264]sh hi + lo      (z-half of gathered FB)
//   phase3b: UbT planes [128][72]sh hi + lo     (g-half, z-contiguous)
// phase3a B-frags from global UaT planes (per-XCD slice 512 KB, L2-hot).
// ---------------------------------------------------------------------------
#define SMEM_WORDS (8704 + 9216 + 1024 + 512 + 128 + 64 + 64 + 8)
#define SMEM_BYTES (SMEM_WORDS * 4)

__global__ __launch_bounds__(512, 4) void fused_kernel(
    const int* __restrict__ cand,
    const unsigned short* __restrict__ Am_hi, const unsigned short* __restrict__ Am_lo,
    const unsigned short* __restrict__ FB_hi, const unsigned short* __restrict__ FB_lo,
    const unsigned short* __restrict__ UaT_hi, const unsigned short* __restrict__ UaT_lo,
    const unsigned* __restrict__ Ub_hl,
    const float* __restrict__ Ta, const float* __restrict__ Tb,
    float* __restrict__ V1, float* __restrict__ V2)
{
  extern __shared__ char smem[];
  unsigned* E    = (unsigned*)smem;          // [128][68] packed hi|lo
  unsigned* SH   = E + 8704;                 // 9216 words, time-shared
  float* vred = (float*)(SH + 9216);         // 1024
  float* csp  = vred + 1024;                 // [8][64]
  float* rrcp = csp + 512;                   // [128]
  float* crcp = rrcp + 128;                  // [64]
  int*   cidx = (int*)(crcp + 64);           // [64]
  float* gmax = (float*)(cidx + 64);         // [8]
  unsigned short* SHs = (unsigned short*)SH;

  const int bc = ((blockIdx.x & 7) << 8) | (blockIdx.x >> 3);  // XCD swizzle (2048%8==0)
  const int b = bc >> 6, t = threadIdx.x;
  const int w = t >> 6, l = t & 63, a = l & 15, hq = l >> 4;

  if (t < 64) cidx[t] = cand[(size_t)bc * 64 + t];
  __syncthreads();

  // ---- phase 1: e = Am[b] @ FB^T, z staged in halves. wave = s-tile w ----
  f4 acc[4];
#pragma unroll
  for (int i = 0; i < 4; ++i)
#pragma unroll
    for (int r = 0; r < 4; ++r) acc[i][r] = 0.f;

  for (int h = 0; h < 2; ++h) {
#pragma unroll
    for (int i = 0; i < 2; ++i) {            // stage 32 z rows, hi+lo planes
      int flat = i * 512 + t;
      int z = flat >> 5, c = flat & 31;
      int row = cidx[h * 32 + z];
      *(uint4*)&SHs[z * 264 + c * 8]        = *(const uint4*)&FB_hi[(size_t)row * 256 + c * 8];
      *(uint4*)&SHs[8448 + z * 264 + c * 8] = *(const uint4*)&FB_lo[(size_t)row * 256 + c * 8];
    }
    __syncthreads();
    const size_t ap = ((size_t)(b * 128 + w * 16 + a)) * 256;
#pragma unroll
    for (int ch = 0; ch < 8; ++ch) {
      int k0 = ch * 32 + hq * 8;
      v8s Ah = *(const v8s*)&Am_hi[ap + k0];
      v8s Al = *(const v8s*)&Am_lo[ap + k0];
#pragma unroll
      for (int zt2 = 0; zt2 < 2; ++zt2) {
        const int zr = (zt2 * 16 + a) * 264 + k0;
        acc[h * 2 + zt2] = mm3p(Ah, Al, *(const v8s*)&SHs[zr],
                                *(const v8s*)&SHs[8448 + zr], acc[h * 2 + zt2]);
      }
    }
    __syncthreads();
  }

  // ---- softmax: global max; E = exp(e-M); rrcp/crcp ----
  {
    float m = -1e30f;
#pragma unroll
    for (int zt = 0; zt < 4; ++zt)
#pragma unroll
      for (int r = 0; r < 4; ++r) m = fmaxf(m, acc[zt][r]);
#pragma unroll
    for (int d = 1; d < 64; d <<= 1) m = fmaxf(m, __shfl_xor(m, d));
    if (l == 0) gmax[w] = m;
    __syncthreads();
    float M = gmax[0];
#pragma unroll
    for (int q = 1; q < 8; ++q) M = fmaxf(M, gmax[q]);

#pragma unroll
    for (int zt = 0; zt < 4; ++zt)
#pragma unroll
      for (int r = 0; r < 4; ++r) acc[zt][r] = __expf(acc[zt][r] - M);

    // rowsum (wave holds full row across zt and lanes a) -> rrcp direct
#pragma unroll
    for (int r = 0; r < 4; ++r) {
      float rs = acc[0][r] + acc[1][r] + acc[2][r] + acc[3][r];
      rs += __shfl_xor(rs, 1); rs += __shfl_xor(rs, 2);
      rs += __shfl_xor(rs, 4); rs += __shfl_xor(rs, 8);
      if (a == 0) rrcp[w * 16 + hq * 4 + r] = 1.f / rs;
    }
    // colsum partial (this wave's 16 s)
#pragma unroll
    for (int zt = 0; zt < 4; ++zt) {
      float c = acc[zt][0] + acc[zt][1] + acc[zt][2] + acc[zt][3];
      c += __shfl_xor(c, 16); c += __shfl_xor(c, 32);
      if (l < 16) csp[w * 64 + zt * 16 + l] = c;
    }
    // packed E write
#pragma unroll
    for (int zt = 0; zt < 4; ++zt)
#pragma unroll
      for (int r = 0; r < 4; ++r)
        E[(w * 16 + hq * 4 + r) * 68 + zt * 16 + a] = pack_hl(acc[zt][r]);
    __syncthreads();
    if (t < 64) {
      float s = 0.f;
#pragma unroll
      for (int q = 0; q < 8; ++q) s += csp[q * 64 + t];
      crcp[t] = 1.f / s;
    }
    __syncthreads();
  }

  // ---- phase 3a: P2 = Et @ Ua; A = E columns (LDS), B = global UaT planes ----
  {
    const int zt = w >> 1, gp = w & 1;
    HL af[4];
#pragma unroll
    for (int ch = 0; ch < 4; ++ch) {
      unsigned q[8];
#pragma unroll
      for (int j = 0; j < 8; ++j)
        q[j] = E[(ch * 32 + hq * 8 + j) * 68 + zt * 16 + a];
      uint4 q0; q0.x = q[0]; q0.y = q[1]; q0.z = q[2]; q0.w = q[3];
      uint4 q1; q1.x = q[4]; q1.y = q[5]; q1.z = q[6]; q1.w = q[7];
      af[ch] = unpack8(q0, q1);
    }
    float crz[4]; const float* tbp[4];
#pragma unroll
    for (int r = 0; r < 4; ++r) {
      int z = zt * 16 + hq * 4 + r;
      crz[r] = crcp[z];
      tbp[r] = Tb + (size_t)cidx[z] * 256;
    }
#pragma unroll
    for (int gt = 0; gt < 8; ++gt) {
      int g = (gp * 8 + gt) * 16 + a;
      const size_t ub = ((size_t)(b * 256 + g)) * 128;
      f4 c = {0.f, 0.f, 0.f, 0.f};
#pragma unroll
      for (int ch = 0; ch < 4; ++ch) {
        int k0 = ch * 32 + hq * 8;
        c = mm3h(af[ch], *(const v8s*)&UaT_hi[ub + k0],
                 *(const v8s*)&UaT_lo[ub + k0], c);
      }
      float sv = 0.f;
#pragma unroll
      for (int r = 0; r < 4; ++r)
        sv += fmaxf(fmaf(c[r], crz[r], tbp[r][g]), 0.f);
      sv += __shfl_xor(sv, 16); sv += __shfl_xor(sv, 32);
      if (l < 16) vred[zt * 256 + g] = sv;
    }
    __syncthreads();
    if (t < 256)
      V2[(size_t)bc * 256 + t] = vred[t] + vred[256 + t] + vred[512 + t] + vred[768 + t];
  }

  // ---- phase 3b: P1 = E @ Ub; Ub staged per g-half as UbT planes ----
  for (int h = 0; h < 2; ++h) {
#pragma unroll
    for (int i = 0; i < 8; ++i) {            // stage: z-pairs x 128 g
      int flat = i * 512 + t;
      int zp = flat >> 7, g = flat & 127;
      unsigned p0 = Ub_hl[(size_t)cidx[zp * 2]     * 256 + h * 128 + g];
      unsigned p1 = Ub_hl[(size_t)cidx[zp * 2 + 1] * 256 + h * 128 + g];
      SH[g * 36 + zp]        = (p0 & 0xffffu) | (p1 << 16);
      SH[4608 + g * 36 + zp] = (p0 >> 16) | (p1 & 0xffff0000u);
    }
    __syncthreads();

    HL af1[2];
#pragma unroll
    for (int ch = 0; ch < 2; ++ch) {
      const unsigned* p = E + (w * 16 + a) * 68 + ch * 32 + hq * 8;
      af1[ch] = unpack8(*(const uint4*)p, *(const uint4*)(p + 4));
    }
    float rr[4]; const float* tap[4];
#pragma unroll
    for (int r = 0; r < 4; ++r) {
      int s = w * 16 + hq * 4 + r;
      rr[r] = rrcp[s];
      tap[r] = Ta + ((size_t)(b * 128 + s)) * 256 + h * 128;
    }
#pragma unroll
    for (int gt = 0; gt < 8; ++gt) {
      int g = gt * 16 + a;
      f4 c = {0.f, 0.f, 0.f, 0.f};
#pragma unroll
      for (int ch = 0; ch < 2; ++ch) {
        int k0 = ch * 32 + hq * 8;
        c = mm3h(af1[ch], *(const v8s*)&SHs[g * 72 + k0],
                 *(const v8s*)&SHs[9216 + g * 72 + k0], c);
      }
      float sv = 0.f;
#pragma unroll
      for (int r = 0; r < 4; ++r)
        sv += fmaxf(fmaf(c[r], rr[r], tap[r][g]), 0.f);
      sv += __shfl_xor(sv, 16); sv += __shfl_xor(sv, 32);
      if (l < 16) vred[w * 128 + g] = sv;
    }
    __syncthreads();
    if (t < 128) {
      float s = 0.f;
#pragma unroll
      for (int q = 0; q < 8; ++q) s += vred[q * 128 + t];
      V1[(size_t)bc * 256 + h * 128 + t] = s;
    }
  }
}

// ---------------------------------------------------------------------------
// y[bc] = V1[bc]·HW[0:256] + V2[bc]·HW[256:512] + Hb
// ---------------------------------------------------------------------------
__global__ __launch_bounds__(256) void final_kernel(
    const float* __restrict__ V1, const float* __restrict__ V2,
    const float* __restrict__ HW, const float* __restrict__ Hb,
    float* __restrict__ y)
{
  const int t = threadIdx.x;
  const int w = t >> 6, l = t & 63;
  const int bc = blockIdx.x * 4 + w;
  float4 v1 = *(const float4*)&V1[(size_t)bc * Dc + l * 4];
  float4 h1 = *(const float4*)&HW[l * 4];
  float4 v2 = *(const float4*)&V2[(size_t)bc * Dc + l * 4];
  float4 h2 = *(const float4*)&HW[Dc + l * 4];
  float sum = v1.x * h1.x + v1.y * h1.y + v1.z * h1.z + v1.w * h1.w
            + v2.x * h2.x + v2.y * h2.y + v2.z * h2.z + v2.w * h2.w;
#pragma unroll
  for (int off = 32; off > 0; off >>= 1) sum += __shfl_down(sum, off);
  if (l == 0) y[bc] = sum + Hb[0];
}

extern "C" void kernel_launch(void* const* d_in, const int* in_sizes, int n_in,
                              void* d_out, int out_size, void* d_ws, size_t ws_size,
                              hipStream_t stream) {
  (void)in_sizes; (void)n_in; (void)out_size; (void)ws_size;
  const int*   inp  = (const int*)d_in[0];
  const int*   cand = (const int*)d_in[1];
  const float* EmbA = (const float*)d_in[4];
  const float* EmbB = (const float*)d_in[5];
  const float* FW   = (const float*)d_in[6];
  const float* Fb   = (const float*)d_in[7];
  const float* GW   = (const float*)d_in[8];
  const float* Gb   = (const float*)d_in[9];
  const float* HW   = (const float*)d_in[10];
  const float* Hb   = (const float*)d_in[11];
  float* y = (float*)d_out;

  const size_t nA = (size_t)Bc * Sc * Dc;   // 1,048,576 elems
  const size_t nB = (size_t)VOc * Dc;       // 1,280,000 elems
  const size_t nV = (size_t)Bc * Cc * Dc;   //   524,288 elems
  char* ws = (char*)d_ws;
  unsigned short* Am_hi = (unsigned short*)ws;              ws += nA * 2;
  unsigned short* Am_lo = (unsigned short*)ws;              ws += nA * 2;
  unsigned short* FB_hi = (unsigned short*)ws;              ws += nB * 2;
  unsigned short* FB_lo = (unsigned short*)ws;              ws += nB * 2;
  unsigned short* UaT_hi = (unsigned short*)ws;             ws += nA * 2;
  unsigned short* UaT_lo = (unsigned short*)ws;             ws += nA * 2;
  unsigned*       Ub_hl  = (unsigned*)ws;                   ws += nB * 4;
  float*          Ta     = (float*)ws;                      ws += nA * 4;
  float*          Tb     = (float*)ws;                      ws += nB * 4;
  float*          V1     = (float*)ws;                      ws += nV * 4;
  float*          V2     = (float*)ws;                      // total ~31.8 MB

  hipFuncSetAttribute((const void*)fused_kernel,
                      hipFuncAttributeMaxDynamicSharedMemorySize, SMEM_BYTES);

  transform_kernel<<<dim3(143, 6), 256, 0, stream>>>(
      EmbA, inp, EmbB, FW, Fb, GW, Gb,
      Am_hi, Am_lo, Ta, UaT_hi, UaT_lo, FB_hi, FB_lo, Tb, Ub_hl);
  fused_kernel<<<Bc * Cc, 512, SMEM_BYTES, stream>>>(
      cand, Am_hi, Am_lo, FB_hi, FB_lo, UaT_hi, UaT_lo, Ub_hl, Ta, Tb, V1, V2);
  final_kernel<<<(Bc * Cc) / 4, 256, 0, stream>>>(V1, V2, HW, Hb, y);
}

// Round 7
// 269.044 us; speedup vs baseline: 1.8945x; 1.3895x over previous
//
#include <hip/hip_runtime.h>
#include <hip/hip_bf16.h>
#include <math.h>

#define Bc 32
#define Cc 64
#define Sc 128
#define Zc 64
#define Dc 256
#define VOc 5000

typedef __attribute__((ext_vector_type(8))) short v8s;   // 8 bf16 = 4 VGPR MFMA frag
typedef __attribute__((ext_vector_type(4))) float f4;    // 16x16 accum

union FQ { uint4 q; v8s s; };
struct HL { v8s hi, lo; };

__device__ __forceinline__ unsigned short bf_bits(__hip_bfloat16 h) {
  union { __hip_bfloat16 b; unsigned short u; } cv; cv.b = h; return cv.u;
}

__device__ __forceinline__ void split_hl(float x, unsigned short& h, unsigned short& l) {
  __hip_bfloat16 hh = __float2bfloat16(x);
  float hf = __bfloat162float(hh);
  __hip_bfloat16 ll = __float2bfloat16(x - hf);
  h = bf_bits(hh); l = bf_bits(ll);
}

__device__ __forceinline__ unsigned pack_hl(float x) {
  unsigned short h, l; split_hl(x, h, l);
  return (unsigned)h | ((unsigned)l << 16);
}

// 8 packed u32 -> hi-frag + lo-frag
__device__ __forceinline__ HL unpack8(uint4 q0, uint4 q1) {
  FQ h, l;
  h.q.x = __builtin_amdgcn_perm(q0.y, q0.x, 0x05040100u);
  h.q.y = __builtin_amdgcn_perm(q0.w, q0.z, 0x05040100u);
  h.q.z = __builtin_amdgcn_perm(q1.y, q1.x, 0x05040100u);
  h.q.w = __builtin_amdgcn_perm(q1.w, q1.z, 0x05040100u);
  l.q.x = __builtin_amdgcn_perm(q0.y, q0.x, 0x07060302u);
  l.q.y = __builtin_amdgcn_perm(q0.w, q0.z, 0x07060302u);
  l.q.z = __builtin_amdgcn_perm(q1.y, q1.x, 0x07060302u);
  l.q.w = __builtin_amdgcn_perm(q1.w, q1.z, 0x07060302u);
  HL r; r.hi = h.s; r.lo = l.s; return r;
}

// 3-term split product (fp32 accum): AhBh + AhBl + AlBh
__device__ __forceinline__ f4 mm3p(v8s ah, v8s al, v8s bh, v8s bl, f4 c) {
  c = __builtin_amdgcn_mfma_f32_16x16x32_bf16(ah, bh, c, 0, 0, 0);
  c = __builtin_amdgcn_mfma_f32_16x16x32_bf16(ah, bl, c, 0, 0, 0);
  c = __builtin_amdgcn_mfma_f32_16x16x32_bf16(al, bh, c, 0, 0, 0);
  return c;
}
__device__ __forceinline__ f4 mm3h(const HL& A, v8s bh, v8s bl, f4 c) {
  return mm3p(A.hi, A.lo, bh, bl, c);
}

// ---------------------------------------------------------------------------
// prep: WT[j][k] = Wseg[k][n] transposed + hi/lo split. j = seg*256+n, 768 rows.
// ---------------------------------------------------------------------------
__global__ __launch_bounds__(256) void prep_kernel(
    const float* __restrict__ FW, const float* __restrict__ GW,
    unsigned short* __restrict__ WT_hi, unsigned short* __restrict__ WT_lo)
{
  const int j = blockIdx.x, t = threadIdx.x;
  const int seg = j >> 8, n = j & 255;
  float v;
  if (seg == 0) v = FW[(size_t)t * 256 + n];
  else if (seg == 1) v = GW[(size_t)t * 256 + n];
  else v = GW[(size_t)(256 + t) * 256 + n];
  unsigned short h, l; split_hl(v, h, l);
  WT_hi[(size_t)j * 256 + t] = h;
  WT_lo[(size_t)j * 256 + t] = l;
}

// ---------------------------------------------------------------------------
// Transform (MFMA 3-term): 64 rows x 128 cols per block, K=256 in chunks of 32.
// blocks [0,64): EmbA gathered; [64,143): EmbB identity. 256 thr, 4 waves.
//  seg0: relu(+Fb) -> Am/FB hi/lo planes
//  seg1: +Gb -> Ta/Tb fp32
//  seg2: taskA -> UaT planes [b][g][s]; taskB -> Ub packed u32
// ---------------------------------------------------------------------------
__global__ __launch_bounds__(256, 4) void transform_kernel(
    const float* __restrict__ EmbA, const int* __restrict__ inp,
    const float* __restrict__ EmbB,
    const unsigned short* __restrict__ WT_hi, const unsigned short* __restrict__ WT_lo,
    const float* __restrict__ Fb, const float* __restrict__ Gb,
    unsigned short* __restrict__ Am_hi, unsigned short* __restrict__ Am_lo,
    float* __restrict__ Ta,
    unsigned short* __restrict__ UaT_hi, unsigned short* __restrict__ UaT_lo,
    unsigned short* __restrict__ FB_hi, unsigned short* __restrict__ FB_lo,
    float* __restrict__ Tb, unsigned* __restrict__ Ub_hl)
{
  const bool taskA = (blockIdx.x < 64);
  const int rb = taskA ? blockIdx.x : (blockIdx.x - 64);
  const int nrows = taskA ? 4096 : 5000;
  const float* __restrict__ Emb = taskA ? EmbA : EmbB;
  const int* __restrict__ idx = taskA ? inp : nullptr;

  const int cb = blockIdx.y;
  const int row0 = rb * 64;
  const int seg = cb >> 1;
  const int colb = (cb & 1) * 128;

  __shared__ unsigned short As_hi[64 * 40], As_lo[64 * 40];
  __shared__ unsigned short Ws_hi[128 * 40], Ws_lo[128 * 40];

  const int t = threadIdx.x;
  const int w = t >> 6, l = t & 63, a = l & 15, hq = l >> 4;

  f4 acc[8];
#pragma unroll
  for (int nt = 0; nt < 8; ++nt)
#pragma unroll
    for (int r = 0; r < 4; ++r) acc[nt][r] = 0.f;

  for (int k0 = 0; k0 < 256; k0 += 32) {
    // stage A chunk (fp32 -> split planes), row-major [row][k]
#pragma unroll
    for (int i = 0; i < 2; ++i) {
      int flat = i * 256 + t;
      int row = flat >> 3, kq = flat & 7;
      int rr = row0 + row; if (rr > nrows - 1) rr = nrows - 1;
      int src = idx ? idx[rr] : rr;
      float4 v = *(const float4*)&Emb[(size_t)src * 256 + k0 + kq * 4];
      unsigned short h0, l0, h1, l1, h2, l2, h3, l3;
      split_hl(v.x, h0, l0); split_hl(v.y, h1, l1);
      split_hl(v.z, h2, l2); split_hl(v.w, h3, l3);
      unsigned short hs[4] = {h0, h1, h2, h3}, ls[4] = {l0, l1, l2, l3};
      *(uint2*)&As_hi[row * 40 + kq * 4] = *(uint2*)hs;
      *(uint2*)&As_lo[row * 40 + kq * 4] = *(uint2*)ls;
    }
    // stage W chunk (pure copy of WT planes), [n][k]
#pragma unroll
    for (int i = 0; i < 4; ++i) {
      int flat = i * 256 + t;
      int pl = flat >> 9, rem = flat & 511;
      int n = rem >> 2, q = rem & 3;
      const unsigned short* Wp = pl ? WT_lo : WT_hi;
      uint4 v = *(const uint4*)&Wp[(size_t)(seg * 256 + colb + n) * 256 + k0 + q * 8];
      *(uint4*)&(pl ? Ws_lo : Ws_hi)[n * 40 + q * 8] = v;
    }
    __syncthreads();
    v8s ah = *(const v8s*)&As_hi[(w * 16 + a) * 40 + hq * 8];
    v8s al = *(const v8s*)&As_lo[(w * 16 + a) * 40 + hq * 8];
    __builtin_amdgcn_s_setprio(1);
#pragma unroll
    for (int nt = 0; nt < 8; ++nt) {
      v8s bh = *(const v8s*)&Ws_hi[(nt * 16 + a) * 40 + hq * 8];
      v8s bl = *(const v8s*)&Ws_lo[(nt * 16 + a) * 40 + hq * 8];
      acc[nt] = mm3p(ah, al, bh, bl, acc[nt]);
    }
    __builtin_amdgcn_s_setprio(0);
    __syncthreads();
  }

  // epilogue: D col = a, row = hq*4 + r
#pragma unroll
  for (int nt = 0; nt < 8; ++nt) {
    int col = colb + nt * 16 + a;
    float b0 = (seg == 0) ? Fb[col] : ((seg == 1) ? Gb[col] : 0.f);
#pragma unroll
    for (int r = 0; r < 4; ++r) {
      int row = row0 + w * 16 + hq * 4 + r;
      if (row >= nrows) continue;
      float v = acc[nt][r];
      if (seg == 0) {
        unsigned short h, lo2;
        split_hl(fmaxf(v + b0, 0.f), h, lo2);
        (taskA ? Am_hi : FB_hi)[(size_t)row * 256 + col] = h;
        (taskA ? Am_lo : FB_lo)[(size_t)row * 256 + col] = lo2;
      } else if (seg == 1) {
        (taskA ? Ta : Tb)[(size_t)row * 256 + col] = v + b0;
      } else if (!taskA) {
        Ub_hl[(size_t)row * 256 + col] = pack_hl(v);
      } else {
        unsigned short h, lo2;
        split_hl(v, h, lo2);
        size_t o = ((size_t)((row >> 7) * 256 + col)) * 128 + (row & 127);
        UaT_hi[o] = h; UaT_lo[o] = lo2;
      }
    }
  }
}

// ---------------------------------------------------------------------------
// Fused per-(b,c) MFMA kernel, 512 threads (8 waves), 2 blocks/CU.
// LDS: E[128][68] u32 (persist); SH 9216 w time-shared:
//   phase1: FB half planes [32 z][264]sh x2 ; phase3a: UaT quarter [64 g][136]sh x2
//   phase3b: UbT packed-pair planes [128 g][36]w x2
// ---------------------------------------------------------------------------
#define SMEM_WORDS (8704 + 9216 + 1024 + 512 + 128 + 64 + 64 + 8)
#define SMEM_BYTES (SMEM_WORDS * 4)

__global__ __launch_bounds__(512, 4) void fused_kernel(
    const int* __restrict__ cand,
    const unsigned short* __restrict__ Am_hi, const unsigned short* __restrict__ Am_lo,
    const unsigned short* __restrict__ FB_hi, const unsigned short* __restrict__ FB_lo,
    const unsigned short* __restrict__ UaT_hi, const unsigned short* __restrict__ UaT_lo,
    const unsigned* __restrict__ Ub_hl,
    const float* __restrict__ Ta, const float* __restrict__ Tb,
    float* __restrict__ V1, float* __restrict__ V2)
{
  extern __shared__ char smem[];
  unsigned* E    = (unsigned*)smem;          // [128][68] packed hi|lo
  unsigned* SH   = E + 8704;                 // 9216 words time-shared
  float* vred = (float*)(SH + 9216);         // 1024
  float* csp  = vred + 1024;                 // [8][64]
  float* rrcp = csp + 512;                   // [128]
  float* crcp = rrcp + 128;                  // [64]
  int*   cidx = (int*)(crcp + 64);           // [64]
  float* gmax = (float*)(cidx + 64);         // [8]
  unsigned short* SHs = (unsigned short*)SH;

  const int bc = ((blockIdx.x & 7) << 8) | (blockIdx.x >> 3);  // XCD swizzle
  const int b = bc >> 6, t = threadIdx.x;
  const int w = t >> 6, l = t & 63, a = l & 15, hq = l >> 4;

  if (t < 64) cidx[t] = cand[(size_t)bc * 64 + t];
  __syncthreads();

  // ---- phase 1: e = Am[b] @ FB^T; A preloaded fully, FB staged in z-halves ----
  uint4 Ah4[8], Al4[8];
  {
    const size_t ap = ((size_t)(b * 128 + w * 16 + a)) * 256;
#pragma unroll
    for (int ch = 0; ch < 8; ++ch) {
      Ah4[ch] = *(const uint4*)&Am_hi[ap + ch * 32 + hq * 8];
      Al4[ch] = *(const uint4*)&Am_lo[ap + ch * 32 + hq * 8];
    }
  }
  f4 acc[4];
#pragma unroll
  for (int i = 0; i < 4; ++i)
#pragma unroll
    for (int r = 0; r < 4; ++r) acc[i][r] = 0.f;

  for (int h = 0; h < 2; ++h) {
#pragma unroll
    for (int i = 0; i < 2; ++i) {            // stage 32 z rows, hi+lo planes
      int flat = i * 512 + t;
      int z = flat >> 5, c = flat & 31;
      int row = cidx[h * 32 + z];
      *(uint4*)&SHs[z * 264 + c * 8]        = *(const uint4*)&FB_hi[(size_t)row * 256 + c * 8];
      *(uint4*)&SHs[8448 + z * 264 + c * 8] = *(const uint4*)&FB_lo[(size_t)row * 256 + c * 8];
    }
    __syncthreads();
    __builtin_amdgcn_s_setprio(1);
#pragma unroll
    for (int ch = 0; ch < 8; ++ch) {
      int k0 = ch * 32 + hq * 8;
      FQ ahf, alf; ahf.q = Ah4[ch]; alf.q = Al4[ch];
#pragma unroll
      for (int zt2 = 0; zt2 < 2; ++zt2) {
        const int zr = (zt2 * 16 + a) * 264 + k0;
        acc[h * 2 + zt2] = mm3p(ahf.s, alf.s, *(const v8s*)&SHs[zr],
                                *(const v8s*)&SHs[8448 + zr], acc[h * 2 + zt2]);
      }
    }
    __builtin_amdgcn_s_setprio(0);
    __syncthreads();
  }

  // ---- softmax: global max; E = exp(e-M); rrcp/crcp ----
  {
    float m = -1e30f;
#pragma unroll
    for (int zt = 0; zt < 4; ++zt)
#pragma unroll
      for (int r = 0; r < 4; ++r) m = fmaxf(m, acc[zt][r]);
#pragma unroll
    for (int d = 1; d < 64; d <<= 1) m = fmaxf(m, __shfl_xor(m, d));
    if (l == 0) gmax[w] = m;
    __syncthreads();
    float M = gmax[0];
#pragma unroll
    for (int q = 1; q < 8; ++q) M = fmaxf(M, gmax[q]);

#pragma unroll
    for (int zt = 0; zt < 4; ++zt)
#pragma unroll
      for (int r = 0; r < 4; ++r) acc[zt][r] = __expf(acc[zt][r] - M);

#pragma unroll
    for (int r = 0; r < 4; ++r) {
      float rs = acc[0][r] + acc[1][r] + acc[2][r] + acc[3][r];
      rs += __shfl_xor(rs, 1); rs += __shfl_xor(rs, 2);
      rs += __shfl_xor(rs, 4); rs += __shfl_xor(rs, 8);
      if (a == 0) rrcp[w * 16 + hq * 4 + r] = 1.f / rs;
    }
#pragma unroll
    for (int zt = 0; zt < 4; ++zt) {
      float c = acc[zt][0] + acc[zt][1] + acc[zt][2] + acc[zt][3];
      c += __shfl_xor(c, 16); c += __shfl_xor(c, 32);
      if (l < 16) csp[w * 64 + zt * 16 + l] = c;
    }
#pragma unroll
    for (int zt = 0; zt < 4; ++zt)
#pragma unroll
      for (int r = 0; r < 4; ++r)
        E[(w * 16 + hq * 4 + r) * 68 + zt * 16 + a] = pack_hl(acc[zt][r]);
    __syncthreads();
    if (t < 64) {
      float s = 0.f;
#pragma unroll
      for (int q = 0; q < 8; ++q) s += csp[q * 64 + t];
      crcp[t] = 1.f / s;
    }
    __syncthreads();
  }

  // ---- phase 3a: P2 = Et @ Ua; UaT staged per g-quarter into LDS ----
  {
    const int zt = w >> 1, gp = w & 1;
    HL af[4];
#pragma unroll
    for (int ch = 0; ch < 4; ++ch) {
      unsigned q[8];
#pragma unroll
      for (int j = 0; j < 8; ++j)
        q[j] = E[(ch * 32 + hq * 8 + j) * 68 + zt * 16 + a];
      uint4 q0; q0.x = q[0]; q0.y = q[1]; q0.z = q[2]; q0.w = q[3];
      uint4 q1; q1.x = q[4]; q1.y = q[5]; q1.z = q[6]; q1.w = q[7];
      af[ch] = unpack8(q0, q1);
    }
    float crz[4]; const float* tbp[4];
#pragma unroll
    for (int r = 0; r < 4; ++r) {
      int z = zt * 16 + hq * 4 + r;
      crz[r] = crcp[z];
      tbp[r] = Tb + (size_t)cidx[z] * 256;
    }
    for (int Q = 0; Q < 4; ++Q) {
#pragma unroll
      for (int i = 0; i < 4; ++i) {          // stage quarter: 64 g x 128 s x2 planes
        int idx4 = i * 512 + t;
        int pl = idx4 >> 10, rem = idx4 & 1023;
        int g = rem >> 4, q = rem & 15;
        const unsigned short* up = pl ? UaT_lo : UaT_hi;
        uint4 v = *(const uint4*)&up[((size_t)(b * 256 + Q * 64 + g)) * 128 + q * 8];
        *(uint4*)&SHs[pl * 8704 + g * 136 + q * 8] = v;
      }
      __syncthreads();
      __builtin_amdgcn_s_setprio(1);
#pragma unroll
      for (int gt2 = 0; gt2 < 2; ++gt2) {
        int gloc = (gp * 2 + gt2) * 16 + a;
        int gg = Q * 64 + gloc;
        f4 c = {0.f, 0.f, 0.f, 0.f};
#pragma unroll
        for (int ch = 0; ch < 4; ++ch) {
          int k0 = ch * 32 + hq * 8;
          c = mm3h(af[ch], *(const v8s*)&SHs[gloc * 136 + k0],
                   *(const v8s*)&SHs[8704 + gloc * 136 + k0], c);
        }
        float sv = 0.f;
#pragma unroll
        for (int r = 0; r < 4; ++r)
          sv += fmaxf(fmaf(c[r], crz[r], tbp[r][gg]), 0.f);
        sv += __shfl_xor(sv, 16); sv += __shfl_xor(sv, 32);
        if (l < 16) vred[zt * 256 + gg] = sv;
      }
      __builtin_amdgcn_s_setprio(0);
      __syncthreads();
    }
    if (t < 256)
      V2[(size_t)bc * 256 + t] = vred[t] + vred[256 + t] + vred[512 + t] + vred[768 + t];
  }

  // ---- phase 3b: P1 = E @ Ub; UbT staged per g-half (conflict-fixed) ----
  for (int h = 0; h < 2; ++h) {
#pragma unroll
    for (int i = 0; i < 8; ++i) {
      int flat = i * 512 + t;
      int c2 = flat & 3, g = (flat >> 2) & 127;
      int zp = i * 4 + c2;
      unsigned p0 = Ub_hl[(size_t)cidx[zp * 2]     * 256 + h * 128 + g];
      unsigned p1 = Ub_hl[(size_t)cidx[zp * 2 + 1] * 256 + h * 128 + g];
      SH[g * 36 + zp]        = (p0 & 0xffffu) | (p1 << 16);
      SH[4608 + g * 36 + zp] = (p0 >> 16) | (p1 & 0xffff0000u);
    }
    __syncthreads();

    HL af1[2];
#pragma unroll
    for (int ch = 0; ch < 2; ++ch) {
      const unsigned* p = E + (w * 16 + a) * 68 + ch * 32 + hq * 8;
      af1[ch] = unpack8(*(const uint4*)p, *(const uint4*)(p + 4));
    }
    float rr[4]; const float* tap[4];
#pragma unroll
    for (int r = 0; r < 4; ++r) {
      int s = w * 16 + hq * 4 + r;
      rr[r] = rrcp[s];
      tap[r] = Ta + ((size_t)(b * 128 + s)) * 256 + h * 128;
    }
    __builtin_amdgcn_s_setprio(1);
#pragma unroll
    for (int gt = 0; gt < 8; ++gt) {
      int g = gt * 16 + a;
      f4 c = {0.f, 0.f, 0.f, 0.f};
#pragma unroll
      for (int ch = 0; ch < 2; ++ch) {
        int k0 = ch * 32 + hq * 8;
        c = mm3h(af1[ch], *(const v8s*)&SHs[g * 72 + k0],
                 *(const v8s*)&SHs[9216 + g * 72 + k0], c);
      }
      float sv = 0.f;
#pragma unroll
      for (int r = 0; r < 4; ++r)
        sv += fmaxf(fmaf(c[r], rr[r], tap[r][g]), 0.f);
      sv += __shfl_xor(sv, 16); sv += __shfl_xor(sv, 32);
      if (l < 16) vred[w * 128 + g] = sv;
    }
    __builtin_amdgcn_s_setprio(0);
    __syncthreads();
    if (t < 128) {
      float s = 0.f;
#pragma unroll
      for (int q = 0; q < 8; ++q) s += vred[q * 128 + t];
      V1[(size_t)bc * 256 + h * 128 + t] = s;
    }
  }
}

// ---------------------------------------------------------------------------
// y[bc] = V1[bc]·HW[0:256] + V2[bc]·HW[256:512] + Hb
// ---------------------------------------------------------------------------
__global__ __launch_bounds__(256) void final_kernel(
    const float* __restrict__ V1, const float* __restrict__ V2,
    const float* __restrict__ HW, const float* __restrict__ Hb,
    float* __restrict__ y)
{
  const int t = threadIdx.x;
  const int w = t >> 6, l = t & 63;
  const int bc = blockIdx.x * 4 + w;
  float4 v1 = *(const float4*)&V1[(size_t)bc * Dc + l * 4];
  float4 h1 = *(const float4*)&HW[l * 4];
  float4 v2 = *(const float4*)&V2[(size_t)bc * Dc + l * 4];
  float4 h2 = *(const float4*)&HW[Dc + l * 4];
  float sum = v1.x * h1.x + v1.y * h1.y + v1.z * h1.z + v1.w * h1.w
            + v2.x * h2.x + v2.y * h2.y + v2.z * h2.z + v2.w * h2.w;
#pragma unroll
  for (int off = 32; off > 0; off >>= 1) sum += __shfl_down(sum, off);
  if (l == 0) y[bc] = sum + Hb[0];
}

extern "C" void kernel_launch(void* const* d_in, const int* in_sizes, int n_in,
                              void* d_out, int out_size, void* d_ws, size_t ws_size,
                              hipStream_t stream) {
  (void)in_sizes; (void)n_in; (void)out_size; (void)ws_size;
  const int*   inp  = (const int*)d_in[0];
  const int*   cand = (const int*)d_in[1];
  const float* EmbA = (const float*)d_in[4];
  const float* EmbB = (const float*)d_in[5];
  const float* FW   = (const float*)d_in[6];
  const float* Fb   = (const float*)d_in[7];
  const float* GW   = (const float*)d_in[8];
  const float* Gb   = (const float*)d_in[9];
  const float* HW   = (const float*)d_in[10];
  const float* Hb   = (const float*)d_in[11];
  float* y = (float*)d_out;

  const size_t nA = (size_t)Bc * Sc * Dc;   // 1,048,576 elems
  const size_t nB = (size_t)VOc * Dc;       // 1,280,000 elems
  const size_t nV = (size_t)Bc * Cc * Dc;   //   524,288 elems
  const size_t nW = (size_t)768 * 256;      //   196,608 elems
  char* ws = (char*)d_ws;
  unsigned short* Am_hi = (unsigned short*)ws;              ws += nA * 2;
  unsigned short* Am_lo = (unsigned short*)ws;              ws += nA * 2;
  unsigned short* FB_hi = (unsigned short*)ws;              ws += nB * 2;
  unsigned short* FB_lo = (unsigned short*)ws;              ws += nB * 2;
  unsigned short* UaT_hi = (unsigned short*)ws;             ws += nA * 2;
  unsigned short* UaT_lo = (unsigned short*)ws;             ws += nA * 2;
  unsigned*       Ub_hl  = (unsigned*)ws;                   ws += nB * 4;
  float*          Ta     = (float*)ws;                      ws += nA * 4;
  float*          Tb     = (float*)ws;                      ws += nB * 4;
  float*          V1     = (float*)ws;                      ws += nV * 4;
  float*          V2     = (float*)ws;                      ws += nV * 4;
  unsigned short* WT_hi  = (unsigned short*)ws;             ws += nW * 2;
  unsigned short* WT_lo  = (unsigned short*)ws;             // total ~33.4 MB

  hipFuncSetAttribute((const void*)fused_kernel,
                      hipFuncAttributeMaxDynamicSharedMemorySize, SMEM_BYTES);

  prep_kernel<<<768, 256, 0, stream>>>(FW, GW, WT_hi, WT_lo);
  transform_kernel<<<dim3(143, 6), 256, 0, stream>>>(
      EmbA, inp, EmbB, WT_hi, WT_lo, Fb, Gb,
      Am_hi, Am_lo, Ta, UaT_hi, UaT_lo, FB_hi, FB_lo, Tb, Ub_hl);
  fused_kernel<<<Bc * Cc, 512, SMEM_BYTES, stream>>>(
      cand, Am_hi, Am_lo, FB_hi, FB_lo, UaT_hi, UaT_lo, Ub_hl, Ta, Tb, V1, V2);
  final_kernel<<<(Bc * Cc) / 4, 256, 0, stream>>>(V1, V2, HW, Hb, y);
}